// Round 11
// baseline (3999.964 us; speedup 1.0000x reference)
//
#include <hip/hip_runtime.h>
#include <math.h>

#define EMB    1024
#define HID    1024
#define BATCH    64
#define SEQ     512

#define NBG      8   // batch groups
#define BTILE    8   // batches per group (NBG*BTILE = 64)
#define NJT     16   // j-tile WGs per batch group
#define JTILE   64   // j per tile

#define SLOT   65536 // floats per exchange slot (64 x 1024); 2 slots in d_ws
#define STEPSZ 65536 // floats per timestep in out (64 x 1024)

typedef float f32x4 __attribute__((ext_vector_type(4)));

// ---------------------------------------------------------------------------
// Kernel A: x_proj GEMM (unchanged).
// ---------------------------------------------------------------------------
__global__ __launch_bounds__(256) void xproj_gemm(
    const float* __restrict__ A,
    const float* __restrict__ W,
    const float* __restrict__ b_ih,
    const float* __restrict__ b_hh,
    float* __restrict__ out)
{
    __shared__ float As[16][68];
    __shared__ float Ws[16][68];

    const int tid = threadIdx.x;
    const int tx  = tid & 15;
    const int ty  = tid >> 4;
    const int m0  = blockIdx.y * 64;
    const int n0  = blockIdx.x * 64;
    const int lrow = tid >> 2;
    const int lk   = (tid & 3) * 4;

    float acc[4][4] = {};

    for (int kt = 0; kt < EMB; kt += 16) {
        float4 av = *(const float4*)&A[(size_t)(m0 + lrow) * EMB + kt + lk];
        float4 wv = *(const float4*)&W[(size_t)(n0 + lrow) * EMB + kt + lk];
        As[lk + 0][lrow] = av.x; As[lk + 1][lrow] = av.y;
        As[lk + 2][lrow] = av.z; As[lk + 3][lrow] = av.w;
        Ws[lk + 0][lrow] = wv.x; Ws[lk + 1][lrow] = wv.y;
        Ws[lk + 2][lrow] = wv.z; Ws[lk + 3][lrow] = wv.w;
        __syncthreads();
        #pragma unroll
        for (int kk = 0; kk < 16; ++kk) {
            float4 a = *(const float4*)&As[kk][ty * 4];
            float4 w = *(const float4*)&Ws[kk][tx * 4];
            acc[0][0] += a.x * w.x; acc[0][1] += a.x * w.y;
            acc[0][2] += a.x * w.z; acc[0][3] += a.x * w.w;
            acc[1][0] += a.y * w.x; acc[1][1] += a.y * w.y;
            acc[1][2] += a.y * w.z; acc[1][3] += a.y * w.w;
            acc[2][0] += a.z * w.x; acc[2][1] += a.z * w.y;
            acc[2][2] += a.z * w.z; acc[2][3] += a.z * w.w;
            acc[3][0] += a.w * w.x; acc[3][1] += a.w * w.y;
            acc[3][2] += a.w * w.z; acc[3][3] += a.w * w.w;
        }
        __syncthreads();
    }

    const int n = n0 + tx * 4;
    float bias[4];
    #pragma unroll
    for (int j = 0; j < 4; ++j) bias[j] = b_ih[n + j] + b_hh[n + j];

    #pragma unroll
    for (int i = 0; i < 4; ++i) {
        const int m = m0 + ty * 4 + i;
        const int b = m >> 9;
        const int s = m & 511;
        float4 o;
        o.x = acc[i][0] + bias[0];
        o.y = acc[i][1] + bias[1];
        o.z = acc[i][2] + bias[2];
        o.w = acc[i][3] + bias[3];
        *(float4*)&out[((size_t)(s * 64 + b) << 10) + n] = o;
    }
}

// ---------------------------------------------------------------------------
// 16-lane VALU DPP sum reduction (all 16 lanes end with the group sum).
// ---------------------------------------------------------------------------
__device__ __forceinline__ float red16(float x) {
    int xi, yi;
    xi = __builtin_bit_cast(int, x);
    yi = __builtin_amdgcn_update_dpp(0, xi, 0xB1, 0xF, 0xF, true);  // quad_perm xor1
    x += __builtin_bit_cast(float, yi);
    xi = __builtin_bit_cast(int, x);
    yi = __builtin_amdgcn_update_dpp(0, xi, 0x4E, 0xF, 0xF, true);  // quad_perm xor2
    x += __builtin_bit_cast(float, yi);
    xi = __builtin_bit_cast(int, x);
    yi = __builtin_amdgcn_update_dpp(0, xi, 0x124, 0xF, 0xF, true); // row_ror:4
    x += __builtin_bit_cast(float, yi);
    xi = __builtin_bit_cast(int, x);
    yi = __builtin_amdgcn_update_dpp(0, xi, 0x128, 0xF, 0xF, true); // row_ror:8
    x += __builtin_bit_cast(float, yi);
    return x;
}

// ASYNC 16B coherent load (sc1, serviced at the LLC). Must be completed via
// a counted vmcnt wait before the result register is read.
__device__ __forceinline__ f32x4 llc_load4_async(const float* p) {
    f32x4 v;
    asm volatile("global_load_dwordx4 %0, %1, off sc1"
                 : "=&v"(v) : "v"(p) : "memory");
    return v;
}

// SYNC variant (waitcnt inside — round-8 lesson).
__device__ __forceinline__ f32x4 llc_load4_sync(const float* p) {
    f32x4 v;
    asm volatile("global_load_dwordx4 %0, %1, off sc1\n\t"
                 "s_waitcnt vmcnt(0)"
                 : "=&v"(v) : "v"(p) : "memory");
    return v;
}

// Counted waits. vmcnt retires IN ORDER, so "outstanding <= N" guarantees
// every op with >= N newer ops after it has completed. We always use
// N <= exact-newer-count (over-wait safe; under-wait impossible).
__device__ __forceinline__ void wait_vm5() {
    asm volatile("s_waitcnt vmcnt(5)" ::: "memory");
    __builtin_amdgcn_sched_barrier(0);
}
__device__ __forceinline__ void wait_vm1() {
    asm volatile("s_waitcnt vmcnt(1)" ::: "memory");
    __builtin_amdgcn_sched_barrier(0);
}

// Raw workgroup barrier draining ONLY lgkmcnt: LDS writes visible, async
// vmem loads stay in flight (unlike __syncthreads which drains vmcnt).
__device__ __forceinline__ void bar_lgkm() {
    asm volatile("s_waitcnt lgkmcnt(0)\n\ts_barrier" ::: "memory");
}

__device__ __forceinline__ bool inrange4(f32x4 v, float lo, float hi) {
    return v.x >= lo && v.x <= hi && v.y >= lo && v.y <= hi &&
           v.z >= lo && v.z <= hi && v.w >= lo && v.w <= hi;
}

// One sub-iteration: batch BB of step t. WAITFN completes the prefetch for
// BB; validate (tag = 4*(tp&3) + 16*((BB>>1)&1), so neither the other t in
// this slot nor the previous occupant of this prefetch REGISTER can ever
// false-validate); stage to LDS; issue prefetch for BB+2; barrier; compute;
// owning lanes (c==2*BB, 2*BB+1) tanh+publish immediately.
#define SUBITER(BB, WAITFN)                                                   \
  do {                                                                        \
    const int   tp  = t - 1;                                                  \
    const float off = 4.0f * (float)(tp & 3)                                  \
                    + 16.0f * (float)(((BB) >> 1) & 1);                       \
    const float lo = off - 1.0f, hi = off + 1.0f;                             \
    const float* ebase = exch + (tp & 1) * SLOT + (bg * BTILE + (BB)) * HID;  \
    WAITFN();                                                                 \
    f32x4& PF = ((BB) & 1) ? pfB : pfA;                                       \
    bool ok = !have || inrange4(PF, lo, hi);                                  \
    while (!__all(ok)) {                                                      \
      if (!ok) { PF = llc_load4_sync(ebase + gq); ok = inrange4(PF, lo, hi); }\
    }                                                                         \
    if (have) *(f32x4*)&hsf[((BB) & 1) * 1088 + ldoff] = PF - off;            \
    {                                                                         \
      const int bn = ((BB) + 2) & 7;                                          \
      const int tn = ((BB) >= 6) ? t + 1 : t;                                 \
      if (tn < SEQ) {                                                         \
        const float* nb = exch + ((tn - 1) & 1) * SLOT                        \
                          + (bg * BTILE + bn) * HID;                          \
        if (have) PF = llc_load4_async(nb + gq);                              \
      }                                                                       \
    }                                                                         \
    bar_lgkm();                                                               \
    {                                                                         \
      const float* base = &hsf[((BB) & 1) * 1088 + c * 68];                   \
      f32x4 s0 = {0.f,0.f,0.f,0.f}, s1 = {0.f,0.f,0.f,0.f};                   \
      _Pragma("unroll")                                                       \
      for (int kq = 0; kq < 16; ++kq) {                                       \
        f32x4 h4 = *(const f32x4*)&base[kq * 4];                              \
        s0 += h4 * wr0[kq]; s1 += h4 * wr1[kq];                               \
      }                                                                       \
      float a0 = (s0.x + s0.y) + (s0.z + s0.w);                               \
      float a1 = (s1.x + s1.y) + (s1.z + s1.w);                               \
      a0 = red16(a0); a1 = red16(a1);                                         \
      if (mybat == (BB)) {                                                    \
        float hv = tanhf(xp + ((c & 1) ? a1 : a0));                           \
        out[(size_t)t * STEPSZ + orow] = hv;                                  \
        __hip_atomic_store(&exch[(t & 1) * SLOT + orow],                      \
                           hv + 4.0f * (float)(t & 3)                         \
                              + 16.0f * (float)(((BB) >> 1) & 1),             \
                           __ATOMIC_RELAXED, __HIP_MEMORY_SCOPE_AGENT);       \
      }                                                                       \
    }                                                                         \
    if ((BB) == 7 && t + 1 < SEQ) xp = out[(size_t)(t + 1) * STEPSZ + orow];  \
  } while (0)

// ---------------------------------------------------------------------------
// Persistent recurrence: 8 interleaved per-batch chains per WG (BTILE=8),
// 2-deep register prefetch with counted vmcnt waits, value-tagged exchange.
// 128 WGs (NJT=16 x NBG=8); each wave's 16 c-lanes own one output each
// (batch = c>>1, j = jbase + (c&1)).
// ---------------------------------------------------------------------------
__global__ __launch_bounds__(512, 2) void rnn_persist(
    const float* __restrict__ Whh,    // HID x HID row-major
    float* __restrict__ out,          // (S, B, HID); xp in, h out (in place)
    float* __restrict__ exch)         // 2*SLOT floats, 0x7F-poisoned per launch
{
    const int tid  = threadIdx.x;
    const int wave = tid >> 6;
    const int lane = tid & 63;
    const int c    = lane & 15;          // K-chunk index (64 floats per chunk)
    const int jt   = blockIdx.x;
    const int bg   = blockIdx.y;
    const int jbase = jt * JTILE + wave * 8 + ((lane >> 4) & 3) * 2;
    const int k0    = c * 64;

    // --- W_hh slice -> registers, pinned ---
    f32x4 wr0[16], wr1[16];
    #pragma unroll
    for (int kq = 0; kq < 16; ++kq) {
        wr0[kq] = *(const f32x4*)&Whh[(size_t)jbase * HID + k0 + kq * 4];
        wr1[kq] = *(const f32x4*)&Whh[(size_t)(jbase + 1) * HID + k0 + kq * 4];
    }
    #pragma unroll
    for (int kq = 0; kq < 16; ++kq) {
        asm volatile("" : "+v"(wr0[kq]));
        asm volatile("" : "+v"(wr1[kq]));
    }

    // double-buffered single-batch staging: 2 x (16 chunks x 68 floats)
    __shared__ float hsf[2 * 1088];

    // staging role: threads 0..255 (waves 0-3) load float4 fidx of the batch
    const bool have  = (tid < 256);
    const int  fidx  = tid & 255;
    const int  ldoff = (fidx >> 4) * 68 + (fidx & 15) * 4;
    const int  gq    = fidx * 4;

    // output ownership: ALL 16 c-lanes own (batch = c>>1, j = jbase+(c&1))
    const int jout  = jbase + (c & 1);
    const int mybat = c >> 1;                                  // 0..7
    const int orow  = (bg * BTILE + mybat) * HID + jout;

    // --- t = 0: h0 = tanh(xp); publish tagged into slot 0 ---
    {
        float h0 = tanhf(out[orow]);
        out[orow] = h0;
        __hip_atomic_store(&exch[orow],
                           h0 + 16.0f * (float)((c >> 2) & 1),  // b-pair tag
                           __ATOMIC_RELAXED, __HIP_MEMORY_SCOPE_AGENT);
    }

    // prime: xp(1) and 2-deep prefetch for (t=1, b=0) and (t=1, b=1)
    float xp = out[(size_t)STEPSZ + orow];

    f32x4 pfA = {0.f,0.f,0.f,0.f}, pfB = {0.f,0.f,0.f,0.f};
    if (have) {
        pfA = llc_load4_async(exch + (bg * BTILE + 0) * HID + gq);
        pfB = llc_load4_async(exch + (bg * BTILE + 1) * HID + gq);
    }

    // --- t = 1 peeled: warm-up counted waits ---
    {
        const int t = 1;
        SUBITER(0, wait_vm1);
        SUBITER(1, wait_vm1);
        SUBITER(2, wait_vm5);
        SUBITER(3, wait_vm5);
        SUBITER(4, wait_vm5);
        SUBITER(5, wait_vm5);
        SUBITER(6, wait_vm5);
        SUBITER(7, wait_vm5);
    }

    // --- t = 2 .. SEQ-1 ---
    for (int t = 2; t < SEQ; ++t) {
        SUBITER(0, wait_vm5);
        SUBITER(1, wait_vm5);
        SUBITER(2, wait_vm5);
        SUBITER(3, wait_vm5);
        SUBITER(4, wait_vm5);
        SUBITER(5, wait_vm5);
        SUBITER(6, wait_vm5);
        SUBITER(7, wait_vm5);
    }
}

// ---------------------------------------------------------------------------
extern "C" void kernel_launch(void* const* d_in, const int* in_sizes, int n_in,
                              void* d_out, int out_size, void* d_ws, size_t ws_size,
                              hipStream_t stream) {
    const float* embeds = (const float*)d_in[0];
    const float* W_ih   = (const float*)d_in[1];
    const float* W_hh   = (const float*)d_in[2];
    const float* b_ih   = (const float*)d_in[3];
    const float* b_hh   = (const float*)d_in[4];
    float* out = (float*)d_out;

    (void)in_sizes; (void)n_in; (void)out_size; (void)ws_size;

    // poison exchange buffer to sentinel 0x7F7F7F7F (outside every tag range);
    // captured in the graph -> re-poisoned every replay.
    hipMemsetAsync(d_ws, 0x7F, 2 * SLOT * sizeof(float), stream);

    // Phase 1: x_proj for all timesteps, written into d_out at [s][b][:]
    dim3 gA(HID / 64, (BATCH * SEQ) / 64);
    xproj_gemm<<<gA, 256, 0, stream>>>(embeds, W_ih, b_ih, b_hh, out);

    // Phase 2: persistent recurrence (8-chain interleave, value-tagged)
    dim3 gR(NJT, NBG);
    rnn_persist<<<gR, 512, 0, stream>>>(W_hh, out, (float*)d_ws);
}

// Round 12
// 2747.013 us; speedup vs baseline: 1.4561x; 1.4561x over previous
//
#include <hip/hip_runtime.h>
#include <math.h>

#define EMB    1024
#define HID    1024
#define BATCH    64
#define SEQ     512

#define NBG     16   // batch groups
#define BTILE    4   // batches per group (NBG*BTILE = 64)
#define NJT     16   // j-tile WGs per batch group
#define JTILE   64   // j per tile

#define SLOT   65536 // floats per exchange slot (64 x 1024); 2 slots in d_ws
#define STEPSZ 65536 // floats per timestep in out (64 x 1024)

typedef float f32x4 __attribute__((ext_vector_type(4)));

// ---------------------------------------------------------------------------
// Kernel A: x_proj GEMM (unchanged).
// ---------------------------------------------------------------------------
__global__ __launch_bounds__(256) void xproj_gemm(
    const float* __restrict__ A,
    const float* __restrict__ W,
    const float* __restrict__ b_ih,
    const float* __restrict__ b_hh,
    float* __restrict__ out)
{
    __shared__ float As[16][68];
    __shared__ float Ws[16][68];

    const int tid = threadIdx.x;
    const int tx  = tid & 15;
    const int ty  = tid >> 4;
    const int m0  = blockIdx.y * 64;
    const int n0  = blockIdx.x * 64;
    const int lrow = tid >> 2;
    const int lk   = (tid & 3) * 4;

    float acc[4][4] = {};

    for (int kt = 0; kt < EMB; kt += 16) {
        float4 av = *(const float4*)&A[(size_t)(m0 + lrow) * EMB + kt + lk];
        float4 wv = *(const float4*)&W[(size_t)(n0 + lrow) * EMB + kt + lk];
        As[lk + 0][lrow] = av.x; As[lk + 1][lrow] = av.y;
        As[lk + 2][lrow] = av.z; As[lk + 3][lrow] = av.w;
        Ws[lk + 0][lrow] = wv.x; Ws[lk + 1][lrow] = wv.y;
        Ws[lk + 2][lrow] = wv.z; Ws[lk + 3][lrow] = wv.w;
        __syncthreads();
        #pragma unroll
        for (int kk = 0; kk < 16; ++kk) {
            float4 a = *(const float4*)&As[kk][ty * 4];
            float4 w = *(const float4*)&Ws[kk][tx * 4];
            acc[0][0] += a.x * w.x; acc[0][1] += a.x * w.y;
            acc[0][2] += a.x * w.z; acc[0][3] += a.x * w.w;
            acc[1][0] += a.y * w.x; acc[1][1] += a.y * w.y;
            acc[1][2] += a.y * w.z; acc[1][3] += a.y * w.w;
            acc[2][0] += a.z * w.x; acc[2][1] += a.z * w.y;
            acc[2][2] += a.z * w.z; acc[2][3] += a.z * w.w;
            acc[3][0] += a.w * w.x; acc[3][1] += a.w * w.y;
            acc[3][2] += a.w * w.z; acc[3][3] += a.w * w.w;
        }
        __syncthreads();
    }

    const int n = n0 + tx * 4;
    float bias[4];
    #pragma unroll
    for (int j = 0; j < 4; ++j) bias[j] = b_ih[n + j] + b_hh[n + j];

    #pragma unroll
    for (int i = 0; i < 4; ++i) {
        const int m = m0 + ty * 4 + i;
        const int b = m >> 9;
        const int s = m & 511;
        float4 o;
        o.x = acc[i][0] + bias[0];
        o.y = acc[i][1] + bias[1];
        o.z = acc[i][2] + bias[2];
        o.w = acc[i][3] + bias[3];
        *(float4*)&out[((size_t)(s * 64 + b) << 10) + n] = o;
    }
}

// ---------------------------------------------------------------------------
// 16-lane VALU DPP sum reduction (all 16 lanes end with the group sum).
// ---------------------------------------------------------------------------
__device__ __forceinline__ float red16(float x) {
    int xi, yi;
    xi = __builtin_bit_cast(int, x);
    yi = __builtin_amdgcn_update_dpp(0, xi, 0xB1, 0xF, 0xF, true);  // quad_perm xor1
    x += __builtin_bit_cast(float, yi);
    xi = __builtin_bit_cast(int, x);
    yi = __builtin_amdgcn_update_dpp(0, xi, 0x4E, 0xF, 0xF, true);  // quad_perm xor2
    x += __builtin_bit_cast(float, yi);
    xi = __builtin_bit_cast(int, x);
    yi = __builtin_amdgcn_update_dpp(0, xi, 0x124, 0xF, 0xF, true); // row_ror:4
    x += __builtin_bit_cast(float, yi);
    xi = __builtin_bit_cast(int, x);
    yi = __builtin_amdgcn_update_dpp(0, xi, 0x128, 0xF, 0xF, true); // row_ror:8
    x += __builtin_bit_cast(float, yi);
    return x;
}

// ASYNC 16B coherent load (sc1, LLC). Completed by a counted vmcnt wait.
__device__ __forceinline__ f32x4 llc_load4_async(const float* p) {
    f32x4 v;
    asm volatile("global_load_dwordx4 %0, %1, off sc1"
                 : "=&v"(v) : "v"(p) : "memory");
    return v;
}

// SYNC variant (waitcnt inside — round-8 lesson). Drains the whole queue;
// after a retry, subsequent counted waits are still-safe upper bounds.
__device__ __forceinline__ f32x4 llc_load4_sync(const float* p) {
    f32x4 v;
    asm volatile("global_load_dwordx4 %0, %1, off sc1\n\t"
                 "s_waitcnt vmcnt(0)"
                 : "=&v"(v) : "v"(p) : "memory");
    return v;
}

// Counted wait: vmcnt retires in order, so "outstanding <= N" completes every
// op with >= N newer ops. N is derived per call site from the exact per-wave
// issue queue (loads AND stores count); always <= exact-newer-count.
#define WAITVM(N) do {                                             \
    asm volatile("s_waitcnt vmcnt(" #N ")" ::: "memory");          \
    __builtin_amdgcn_sched_barrier(0);                             \
} while (0)

// Raw WG barrier draining ONLY lgkmcnt: LDS writes visible, async vmem
// loads/stores stay in flight (unlike __syncthreads which drains vmcnt).
__device__ __forceinline__ void bar_lgkm() {
    asm volatile("s_waitcnt lgkmcnt(0)\n\ts_barrier" ::: "memory");
}

__device__ __forceinline__ bool inrange4(f32x4 v, float lo, float hi) {
    return v.x >= lo && v.x <= hi && v.y >= lo && v.y <= hi &&
           v.z >= lo && v.z <= hi && v.w >= lo && v.w <= hi;
}

// One sub-iteration: batch BB of step t, distance-2 prefetch (pf[BB&1] was
// issued at sub BB-2), counted wait WN. Queue math (steady state, per wave):
// newer-than-target = 2 publish stores + 1 prefetch + (xp at b==1) + 2 more
// stores -> vmcnt(5) at b=0/1, vmcnt(6) at b=2/3. Publish stores are never
// the wait target -> producer never blocks on store-ack.
#define SUBITER(BB, WN)                                                       \
  do {                                                                        \
    const int   tp  = t - 1;                                                  \
    const float off = 4.0f * (float)(tp & 3);                                 \
    const float lo = off - 1.0f, hi = off + 1.0f;                             \
    const float* ebase = exch + (tp & 1) * SLOT + (bg * BTILE + (BB)) * HID;  \
    WAITVM(WN);                                                               \
    f32x4& PF = ((BB) & 1) ? pfB : pfA;                                       \
    bool ok = !have || inrange4(PF, lo, hi);                                  \
    while (!__all(ok)) {                                                      \
      if (!ok) { PF = llc_load4_sync(ebase + gq); ok = inrange4(PF, lo, hi); }\
    }                                                                         \
    if (have) *(f32x4*)&hsf[((BB) & 1) * 1088 + ldoff] = PF - off;            \
    {                                                                         \
      const int bn = ((BB) + 2) & 3;                                          \
      const int tn = ((BB) >= 2) ? t + 1 : t;                                 \
      if (tn < SEQ) {                                                         \
        const float* nb = exch + ((tn - 1) & 1) * SLOT                        \
                          + (bg * BTILE + bn) * HID;                          \
        if (have) PF = llc_load4_async(nb + gq);                              \
      }                                                                       \
    }                                                                         \
    if ((BB) == 1 && t + 1 < SEQ) {                                           \
      if (c < 8) xp_next = out[(size_t)(t + 1) * STEPSZ + orow];              \
    }                                                                         \
    bar_lgkm();                                                               \
    {                                                                         \
      const float* base = &hsf[((BB) & 1) * 1088 + c * 68];                   \
      f32x4 s0 = {0.f,0.f,0.f,0.f}, s1 = {0.f,0.f,0.f,0.f};                   \
      _Pragma("unroll")                                                       \
      for (int kq = 0; kq < 16; ++kq) {                                       \
        f32x4 h4 = *(const f32x4*)&base[kq * 4];                              \
        s0 += h4 * wr0[kq]; s1 += h4 * wr1[kq];                               \
      }                                                                       \
      float a0 = (s0.x + s0.y) + (s0.z + s0.w);                               \
      float a1 = (s1.x + s1.y) + (s1.z + s1.w);                               \
      a0 = red16(a0); a1 = red16(a1);                                         \
      if (mybat == (BB)) {                                                    \
        float hv = tanhf(xp_cur + ((c & 1) ? a1 : a0));                       \
        out[(size_t)t * STEPSZ + orow] = hv;                                  \
        __hip_atomic_store(&exch[(t & 1) * SLOT + orow],                      \
                           hv + 4.0f * (float)(t & 3),                        \
                           __ATOMIC_RELAXED, __HIP_MEMORY_SCOPE_AGENT);       \
      }                                                                       \
    }                                                                         \
  } while (0)

// ---------------------------------------------------------------------------
// Persistent recurrence: round-10 geometry (256 WGs, BTILE=4, value-tagged
// exchange) + distance-2 register prefetch + counted vmcnt waits.
// ---------------------------------------------------------------------------
__global__ __launch_bounds__(512, 2) void rnn_persist(
    const float* __restrict__ Whh,    // HID x HID row-major
    float* __restrict__ out,          // (S, B, HID); xp in, h out (in place)
    float* __restrict__ exch)         // 2*SLOT floats, 0x7F-poisoned per launch
{
    const int tid  = threadIdx.x;
    const int wave = tid >> 6;
    const int lane = tid & 63;
    const int c    = lane & 15;          // K-chunk index (64 floats per chunk)
    const int jt   = blockIdx.x;
    const int bg   = blockIdx.y;
    const int jbase = jt * JTILE + wave * 8 + ((lane >> 4) & 3) * 2;
    const int k0    = c * 64;

    // --- W_hh slice -> registers, pinned ---
    f32x4 wr0[16], wr1[16];
    #pragma unroll
    for (int kq = 0; kq < 16; ++kq) {
        wr0[kq] = *(const f32x4*)&Whh[(size_t)jbase * HID + k0 + kq * 4];
        wr1[kq] = *(const f32x4*)&Whh[(size_t)(jbase + 1) * HID + k0 + kq * 4];
    }
    #pragma unroll
    for (int kq = 0; kq < 16; ++kq) {
        asm volatile("" : "+v"(wr0[kq]));
        asm volatile("" : "+v"(wr1[kq]));
    }

    // double-buffered single-batch staging: 2 x (16 chunks x 68 floats)
    __shared__ float hsf[2 * 1088];

    // staging role: threads 0..255 load float4 fidx of the current batch
    const bool have  = (tid < 256);
    const int  fidx  = tid & 255;
    const int  ldoff = (fidx >> 4) * 68 + (fidx & 15) * 4;
    const int  gq    = fidx * 4;

    // output ownership: lanes c<8 own (batch = c>>1, j = jbase + (c&1))
    const int jout  = jbase + (c & 1);
    const int mybat = c >> 1;
    const int orow  = (bg * BTILE + mybat) * HID + jout;

    // --- t = 0: h0 = tanh(xp); publish tag 0 into slot 0 ---
    if (c < 8) {
        float h0 = tanhf(out[orow]);
        out[orow] = h0;
        __hip_atomic_store(&exch[orow], h0, __ATOMIC_RELAXED,
                           __HIP_MEMORY_SCOPE_AGENT);
    }

    // prime (queue order matters for the warm-up counted waits):
    // [t0 stores(2)] -> xp_cur -> pfA(1,b0) -> pfB(1,b1)
    float xp_cur = 0.f, xp_next = 0.f;
    if (c < 8) xp_cur = out[(size_t)STEPSZ + orow];

    f32x4 pfA = {0.f,0.f,0.f,0.f}, pfB = {0.f,0.f,0.f,0.f};
    if (have) {
        pfA = llc_load4_async(exch + (bg * BTILE + 0) * HID + gq);
        pfB = llc_load4_async(exch + (bg * BTILE + 1) * HID + gq);
    }

    // --- t = 1 peeled (warm-up waits: 1, 3, then steady 6) ---
    {
        const int t = 1;
        SUBITER(0, 1);
        SUBITER(1, 3);
        SUBITER(2, 6);
        SUBITER(3, 6);
        xp_cur = xp_next;
    }

    // --- t = 2 .. SEQ-1 (steady waits 5,5,6,6) ---
    for (int t = 2; t < SEQ; ++t) {
        SUBITER(0, 5);
        SUBITER(1, 5);
        SUBITER(2, 6);
        SUBITER(3, 6);
        xp_cur = xp_next;
    }
}

// ---------------------------------------------------------------------------
extern "C" void kernel_launch(void* const* d_in, const int* in_sizes, int n_in,
                              void* d_out, int out_size, void* d_ws, size_t ws_size,
                              hipStream_t stream) {
    const float* embeds = (const float*)d_in[0];
    const float* W_ih   = (const float*)d_in[1];
    const float* W_hh   = (const float*)d_in[2];
    const float* b_ih   = (const float*)d_in[3];
    const float* b_hh   = (const float*)d_in[4];
    float* out = (float*)d_out;

    (void)in_sizes; (void)n_in; (void)out_size; (void)ws_size;

    // poison exchange buffer to sentinel 0x7F7F7F7F (outside every tag range);
    // captured in the graph -> re-poisoned every replay.
    hipMemsetAsync(d_ws, 0x7F, 2 * SLOT * sizeof(float), stream);

    // Phase 1: x_proj for all timesteps, written into d_out at [s][b][:]
    dim3 gA(HID / 64, (BATCH * SEQ) / 64);
    xproj_gemm<<<gA, 256, 0, stream>>>(embeds, W_ih, b_ih, b_hh, out);

    // Phase 2: persistent recurrence (distance-2 prefetch, counted waits)
    dim3 gR(NJT, NBG);
    rnn_persist<<<gR, 512, 0, stream>>>(W_hh, out, (float*)d_ws);
}

// Round 14
// 2538.834 us; speedup vs baseline: 1.5755x; 1.0820x over previous
//
#include <hip/hip_runtime.h>
#include <math.h>

#define EMB    1024
#define HID    1024
#define BATCH    64
#define SEQ     512

#define NBG     16   // batch groups
#define BTILE    4   // batches per group
#define NJT     16   // j-tile WGs per batch group
#define JTILE   64   // j per tile

#define SLOT   65536 // floats per exchange slot; 2 slots in d_ws
#define STEPSZ 65536 // floats per timestep in out

typedef float f32x4 __attribute__((ext_vector_type(4)));
typedef float f32x2 __attribute__((ext_vector_type(2)));

// ---------------------------------------------------------------------------
// 16-lane VALU DPP sum reduction (all 16 lanes end with the group sum).
// ---------------------------------------------------------------------------
__device__ __forceinline__ float red16(float x) {
    int xi, yi;
    xi = __builtin_bit_cast(int, x);
    yi = __builtin_amdgcn_update_dpp(0, xi, 0xB1, 0xF, 0xF, true);  // quad_perm xor1
    x += __builtin_bit_cast(float, yi);
    xi = __builtin_bit_cast(int, x);
    yi = __builtin_amdgcn_update_dpp(0, xi, 0x4E, 0xF, 0xF, true);  // quad_perm xor2
    x += __builtin_bit_cast(float, yi);
    xi = __builtin_bit_cast(int, x);
    yi = __builtin_amdgcn_update_dpp(0, xi, 0x124, 0xF, 0xF, true); // row_ror:4
    x += __builtin_bit_cast(float, yi);
    xi = __builtin_bit_cast(int, x);
    yi = __builtin_amdgcn_update_dpp(0, xi, 0x128, 0xF, 0xF, true); // row_ror:8
    x += __builtin_bit_cast(float, yi);
    return x;
}

// SYNC 16B coherent loads from the LLC (waitcnt inside — round-8 lesson).
__device__ __forceinline__ f32x4 llc_load4_sync(const float* p) {
    f32x4 v;
    asm volatile("global_load_dwordx4 %0, %1, off sc1\n\t"
                 "s_waitcnt vmcnt(0)"
                 : "=&v"(v) : "v"(p) : "memory");
    return v;
}
__device__ __forceinline__ void llc_load4x2_sync(const float* p0, const float* p1,
                                                 f32x4& a, f32x4& b) {
    asm volatile("global_load_dwordx4 %0, %2, off sc1\n\t"
                 "global_load_dwordx4 %1, %3, off sc1\n\t"
                 "s_waitcnt vmcnt(0)"
                 : "=&v"(a), "=&v"(b) : "v"(p0), "v"(p1) : "memory");
}
__device__ __forceinline__ bool inrange4(f32x4 v, float lo, float hi) {
    return v.x >= lo && v.x <= hi && v.y >= lo && v.y <= hi &&
           v.z >= lo && v.z <= hi && v.w >= lo && v.w <= hi;
}

// ---------------------------------------------------------------------------
// FUSED kernel, zero new cross-WG dependencies.
//  - h exchange: r9 value-tagged sc1 protocol (tag 4*(t%4), slot t%2, 0x7F
//    sentinel) — the ONLY cross-WG communication.
//  - xp: each WG computes its OWN slice (4 batches x 64 j, all 512 s) with a
//    per-step 64m x 64n x 64k quantum; s-block [32+16i, 48+16i) is computed
//    during steps 16i+1..16i+16 (done 16 steps before first use); s<32 in a
//    prologue. xp produced/consumed by the SAME WG via plain cached memory.
// ---------------------------------------------------------------------------
__global__ __launch_bounds__(512, 2) void rnn_fused(
    const float* __restrict__ embeds,  // (64,512,1024): row b*512+s
    const float* __restrict__ W_ih,    // HID x EMB
    const float* __restrict__ Whh,     // HID x HID
    const float* __restrict__ b_ih,
    const float* __restrict__ b_hh,
    float* __restrict__ out,           // (S,B,HID); xp then h in place
    float* __restrict__ exch)          // 2*SLOT floats, 0x7F-poisoned
{
    const int tid  = threadIdx.x;
    const int wave = tid >> 6;
    const int lane = tid & 63;
    const int c    = lane & 15;
    const int jt   = blockIdx.x;
    const int bg   = blockIdx.y;
    const int jbase = jt * JTILE + wave * 8 + ((lane >> 4) & 3) * 2;
    const int k0    = c * 64;

    // --- W_hh slice -> registers, pinned ---
    f32x4 wr0[16], wr1[16];
    #pragma unroll
    for (int kq = 0; kq < 16; ++kq) {
        wr0[kq] = *(const f32x4*)&Whh[(size_t)jbase * HID + k0 + kq * 4];
        wr1[kq] = *(const f32x4*)&Whh[(size_t)(jbase + 1) * HID + k0 + kq * 4];
    }
    #pragma unroll
    for (int kq = 0; kq < 16; ++kq) {
        asm volatile("" : "+v"(wr0[kq]));
        asm volatile("" : "+v"(wr1[kq]));
    }

    // LDS: h double-buffer (34.8KB) + xp A/W double-buffers (2x34.8KB)
    __shared__ float hsf[2 * 4352];
    __shared__ float Axs[2][64][68];   // [k][m], m = si*4+bloc
    __shared__ float Wxs[2][64][68];   // [k][n]

    // h staging (r9): thread handles float4 idx tid and tid+512
    const int b0i = tid >> 8,         r0 = tid & 255;
    const int b1i = (tid + 512) >> 8, r1 = (tid + 512) & 255;
    const int exoff0 = (bg * BTILE + b0i) * HID + r0 * 4;
    const int exoff1 = (bg * BTILE + b1i) * HID + r1 * 4;
    const int ldo0 = b0i * 1088 + (r0 >> 4) * 68 + (r0 & 15) * 4;
    const int ldo1 = b1i * 1088 + (r1 >> 4) * 68 + (r1 & 15) * 4;

    // output ownership: lanes c<8 own (batch = c>>1, j = jbase + (c&1))
    const int jout  = jbase + (c & 1);
    const int mybat = c >> 1;
    const int orow  = (bg * BTILE + mybat) * HID + jout;

    // xp-GEMM mapping: 512 thr = 16 gty x 32 gtx; micro 4m x 2n.
    // m = gty*4+mi -> (s = sbase+gty, b = bg*4+mi); n = gtx*2+ni.
    const int gty = tid >> 5;
    const int gtx = tid & 31;
    const int jx0 = jt * 64 + gtx * 2;
    const float bias0 = b_ih[jx0] + b_hh[jx0];
    const float bias1 = b_ih[jx0 + 1] + b_hh[jx0 + 1];
    // staging: thread loads f = 2*tid, 2*tid+1 of 1024 f32x4 (m=f>>4,k4=f&15)
    const int fm0 = (2 * tid) >> 4,     fk0 = (2 * tid) & 15;
    const int fm1 = (2 * tid + 1) >> 4, fk1 = (2 * tid + 1) & 15;

    f32x4 xaccA = {0.f,0.f,0.f,0.f};   // ni=0, lanes mi
    f32x4 xaccB = {0.f,0.f,0.f,0.f};   // ni=1

    // write one staged pair into LDS buffer `buf`
    auto xp_write = [&](int buf, f32x4 av0, f32x4 wv0, f32x4 av1, f32x4 wv1) {
        Axs[buf][fk0*4+0][fm0]=av0.x; Axs[buf][fk0*4+1][fm0]=av0.y;
        Axs[buf][fk0*4+2][fm0]=av0.z; Axs[buf][fk0*4+3][fm0]=av0.w;
        Wxs[buf][fk0*4+0][fm0]=wv0.x; Wxs[buf][fk0*4+1][fm0]=wv0.y;
        Wxs[buf][fk0*4+2][fm0]=wv0.z; Wxs[buf][fk0*4+3][fm0]=wv0.w;
        Axs[buf][fk1*4+0][fm1]=av1.x; Axs[buf][fk1*4+1][fm1]=av1.y;
        Axs[buf][fk1*4+2][fm1]=av1.z; Axs[buf][fk1*4+3][fm1]=av1.w;
        Wxs[buf][fk1*4+0][fm1]=wv1.x; Wxs[buf][fk1*4+1][fm1]=wv1.y;
        Wxs[buf][fk1*4+2][fm1]=wv1.z; Wxs[buf][fk1*4+3][fm1]=wv1.w;
    };
    auto xp_lda = [&](int sbase, int kc, int fm, int fk) -> f32x4 {
        return *(const f32x4*)&embeds[
            ((size_t)((bg*4 + (fm & 3)) * 512 + sbase + (fm >> 2)) << 10) + kc + fk*4];
    };
    auto xp_ldw = [&](int kc, int fm, int fk) -> f32x4 {
        return *(const f32x4*)&W_ih[((size_t)(jt*64 + fm) << 10) + kc + fk*4];
    };
    auto xp_compute = [&](int buf) {
        #pragma unroll
        for (int kk = 0; kk < 64; ++kk) {
            f32x4 a4 = *(const f32x4*)&Axs[buf][kk][gty * 4];
            f32x2 w2 = *(const f32x2*)&Wxs[buf][kk][gtx * 2];
            xaccA += a4 * w2.x;
            xaccB += a4 * w2.y;
        }
    };
    auto xp_store = [&](int sbase) {
        float* o = &out[((size_t)((sbase + gty) * 64 + bg * 4) << 10) + jx0];
        *(f32x2*)(o +    0) = f32x2{xaccA.x + bias0, xaccB.x + bias1};
        *(f32x2*)(o + 1024) = f32x2{xaccA.y + bias0, xaccB.y + bias1};
        *(f32x2*)(o + 2048) = f32x2{xaccA.z + bias0, xaccB.z + bias1};
        *(f32x2*)(o + 3072) = f32x2{xaccA.w + bias0, xaccB.w + bias1};
        xaccA = f32x4{0.f,0.f,0.f,0.f};
        xaccB = f32x4{0.f,0.f,0.f,0.f};
    };

    // --- prologue: xp for s in [0,32), 32 quanta ---
    for (int q = 0; q < 32; ++q) {
        const int sb = (q >> 4) << 4;
        const int kc = (q & 15) << 6;
        xp_write(q & 1, xp_lda(sb, kc, fm0, fk0), xp_ldw(kc, fm0, fk0),
                        xp_lda(sb, kc, fm1, fk1), xp_ldw(kc, fm1, fk1));
        __syncthreads();
        xp_compute(q & 1);
        if ((q & 15) == 15) xp_store(sb);
    }
    __syncthreads();

    // --- t = 0: h0 = tanh(xp0); publish tag 0 into slot 0 ---
    if (c < 8) {
        float h0 = tanhf(out[orow]);
        out[orow] = h0;
        __hip_atomic_store(&exch[orow], h0, __ATOMIC_RELAXED,
                           __HIP_MEMORY_SCOPE_AGENT);
    }

    // --- t = 1 .. SEQ-1 ---
    for (int t = 1; t < SEQ; ++t) {
        float* cur = out + (size_t)t * STEPSZ;

        // xp for this step (self-written >=16 steps ago; plain cached load)
        float xp = 0.f;
        if (c < 8) xp = cur[orow];

        // issue xp staging loads for quantum q = t-1 (hidden under the poll)
        const bool doxp = (t <= 480);
        const int  q    = t - 1;
        const int  xbuf = q & 1;
        const int  sb   = 32 + (q & ~15);
        const int  kc   = (q & 15) << 6;
        f32x4 av0, wv0, av1, wv1;
        if (doxp) {
            av0 = xp_lda(sb, kc, fm0, fk0); wv0 = xp_ldw(kc, fm0, fk0);
            av1 = xp_lda(sb, kc, fm1, fk1); wv1 = xp_ldw(kc, fm1, fk1);
            __builtin_amdgcn_sched_barrier(0);
        }

        // poll + fetch h(t-1) — r9 value-tagged protocol
        const float off = 4.0f * (float)((t - 1) & 3);
        const float lo  = off - 1.0f, hi = off + 1.0f;
        const float* eb = exch + ((t - 1) & 1) * SLOT;
        f32x4 v0, v1;
        llc_load4x2_sync(eb + exoff0, eb + exoff1, v0, v1);
        bool ok0 = inrange4(v0, lo, hi);
        bool ok1 = inrange4(v1, lo, hi);
        while (!__all(ok0 && ok1)) {
            __builtin_amdgcn_s_sleep(1);
            if (!ok0) { v0 = llc_load4_sync(eb + exoff0); ok0 = inrange4(v0, lo, hi); }
            if (!ok1) { v1 = llc_load4_sync(eb + exoff1); ok1 = inrange4(v1, lo, hi); }
        }
        v0 -= off;
        v1 -= off;

        // stage h + stage xp, one barrier
        const int bufb = (t & 1) * 4352;
        *(f32x4*)&hsf[bufb + ldo0] = v0;
        *(f32x4*)&hsf[bufb + ldo1] = v1;
        if (doxp) xp_write(xbuf, av0, wv0, av1, wv1);
        __syncthreads();

        // h compute (r9)
        float acc[4][2];
        #pragma unroll
        for (int b = 0; b < 4; ++b) {
            const f32x4* hb = (const f32x4*)&hsf[bufb + b * 1088 + c * 68];
            f32x4 s0 = {0.f,0.f,0.f,0.f}, s1 = {0.f,0.f,0.f,0.f};
            #pragma unroll
            for (int kq = 0; kq < 16; ++kq) {
                f32x4 h4 = hb[kq];
                s0 += h4 * wr0[kq];
                s1 += h4 * wr1[kq];
            }
            acc[b][0] = (s0.x + s0.y) + (s0.z + s0.w);
            acc[b][1] = (s1.x + s1.y) + (s1.z + s1.w);
        }
        #pragma unroll
        for (int b = 0; b < 4; ++b) {
            acc[b][0] = red16(acc[b][0]);
            acc[b][1] = red16(acc[b][1]);
        }
        float vb0 = (c & 1) ? acc[0][1] : acc[0][0];
        float vb1 = (c & 1) ? acc[1][1] : acc[1][0];
        float vb2 = (c & 1) ? acc[2][1] : acc[2][0];
        float vb3 = (c & 1) ? acc[3][1] : acc[3][0];
        float vlo = (c & 2) ? vb1 : vb0;
        float vhi = (c & 2) ? vb3 : vb2;
        float v   = (c & 4) ? vhi : vlo;
        if (c < 8) {
            float hv = tanhf(xp + v);
            cur[orow] = hv;
            __hip_atomic_store(&exch[(t & 1) * SLOT + orow],
                               hv + 4.0f * (float)(t & 3),
                               __ATOMIC_RELAXED, __HIP_MEMORY_SCOPE_AGENT);
        }

        // xp quantum compute (overlaps the h-exchange turnaround)
        if (doxp) {
            xp_compute(xbuf);
            if ((t & 15) == 0) xp_store(sb);   // q&15==15 -> block complete
        }
    }
}

// ---------------------------------------------------------------------------
extern "C" void kernel_launch(void* const* d_in, const int* in_sizes, int n_in,
                              void* d_out, int out_size, void* d_ws, size_t ws_size,
                              hipStream_t stream) {
    const float* embeds = (const float*)d_in[0];
    const float* W_ih   = (const float*)d_in[1];
    const float* W_hh   = (const float*)d_in[2];
    const float* b_ih   = (const float*)d_in[3];
    const float* b_hh   = (const float*)d_in[4];
    float* out = (float*)d_out;

    (void)in_sizes; (void)n_in; (void)out_size; (void)ws_size;

    // poison exchange buffer (outside every tag range); graph-captured so
    // re-armed on every replay.
    hipMemsetAsync(d_ws, 0x7F, (size_t)2 * SLOT * sizeof(float), stream);

    // single fused dispatch
    dim3 gR(NJT, NBG);
    rnn_fused<<<gR, 512, 0, stream>>>(embeds, W_ih, W_hh, b_ih, b_hh,
                                      out, (float*)d_ws);
}

// Round 15
// 2355.572 us; speedup vs baseline: 1.6981x; 1.0778x over previous
//
#include <hip/hip_runtime.h>
#include <math.h>

#define EMB    1024
#define HID    1024
#define BATCH    64
#define SEQ     512

#define NBG     16   // batch groups
#define BTILE    4   // batches per group
#define NJT     16   // j-tile WGs per batch group
#define JTILE   64   // j per tile

#define SLOT   65536 // floats per exchange slot; 2 slots in d_ws
#define STEPSZ 65536 // floats per timestep in out

typedef float f32x4 __attribute__((ext_vector_type(4)));
typedef float f32x2 __attribute__((ext_vector_type(2)));

// ---------------------------------------------------------------------------
// 16-lane VALU DPP sum reduction (all 16 lanes end with the group sum).
// ---------------------------------------------------------------------------
__device__ __forceinline__ float red16(float x) {
    int xi, yi;
    xi = __builtin_bit_cast(int, x);
    yi = __builtin_amdgcn_update_dpp(0, xi, 0xB1, 0xF, 0xF, true);  // quad_perm xor1
    x += __builtin_bit_cast(float, yi);
    xi = __builtin_bit_cast(int, x);
    yi = __builtin_amdgcn_update_dpp(0, xi, 0x4E, 0xF, 0xF, true);  // quad_perm xor2
    x += __builtin_bit_cast(float, yi);
    xi = __builtin_bit_cast(int, x);
    yi = __builtin_amdgcn_update_dpp(0, xi, 0x124, 0xF, 0xF, true); // row_ror:4
    x += __builtin_bit_cast(float, yi);
    xi = __builtin_bit_cast(int, x);
    yi = __builtin_amdgcn_update_dpp(0, xi, 0x128, 0xF, 0xF, true); // row_ror:8
    x += __builtin_bit_cast(float, yi);
    return x;
}

// SYNC 16B coherent loads from the LLC (waitcnt inside — round-8 lesson).
__device__ __forceinline__ f32x4 llc_load4_sync(const float* p) {
    f32x4 v;
    asm volatile("global_load_dwordx4 %0, %1, off sc1\n\t"
                 "s_waitcnt vmcnt(0)"
                 : "=&v"(v) : "v"(p) : "memory");
    return v;
}
__device__ __forceinline__ void llc_load4x2_sync(const float* p0, const float* p1,
                                                 f32x4& a, f32x4& b) {
    asm volatile("global_load_dwordx4 %0, %2, off sc1\n\t"
                 "global_load_dwordx4 %1, %3, off sc1\n\t"
                 "s_waitcnt vmcnt(0)"
                 : "=&v"(a), "=&v"(b) : "v"(p0), "v"(p1) : "memory");
}
__device__ __forceinline__ bool inrange4(f32x4 v, float lo, float hi) {
    return v.x >= lo && v.x <= hi && v.y >= lo && v.y <= hi &&
           v.z >= lo && v.z <= hi && v.w >= lo && v.w <= hi;
}

// ---------------------------------------------------------------------------
// FUSED kernel (r14 structure), xp staging rewritten CONFLICT-FREE:
//  - h exchange: r9 value-tagged sc1 protocol — only cross-WG communication.
//  - xp: each WG computes its OWN slice; per-step 64m x 64n x 64k quantum;
//    s-block [32+16i,48+16i) computed during steps 16i+1..16i+16; s<32 in a
//    prologue. Same-WG produce/consume via plain cached memory.
//  - Staging mapping (the r0 xproj_gemm pattern, measured 0 conflicts):
//    tid<256 -> A, tid>=256 -> W; row srow=(tid&255)>>2, kofs=(tid&3)*4,
//    4 slabs of 16k. Write bank = ((tid&3)*16 + 4j + tid>>2) mod 32 ->
//    2-way aliasing only (free). 4 consecutive lanes read 64B of one row.
// ---------------------------------------------------------------------------
__global__ __launch_bounds__(512, 2) void rnn_fused(
    const float* __restrict__ embeds,  // (64,512,1024): row b*512+s
    const float* __restrict__ W_ih,    // HID x EMB
    const float* __restrict__ Whh,     // HID x HID
    const float* __restrict__ b_ih,
    const float* __restrict__ b_hh,
    float* __restrict__ out,           // (S,B,HID); xp then h in place
    float* __restrict__ exch)          // 2*SLOT floats, 0x7F-poisoned
{
    const int tid  = threadIdx.x;
    const int wave = tid >> 6;
    const int lane = tid & 63;
    const int c    = lane & 15;
    const int jt   = blockIdx.x;
    const int bg   = blockIdx.y;
    const int jbase = jt * JTILE + wave * 8 + ((lane >> 4) & 3) * 2;
    const int k0    = c * 64;

    // --- W_hh slice -> registers, pinned ---
    f32x4 wr0[16], wr1[16];
    #pragma unroll
    for (int kq = 0; kq < 16; ++kq) {
        wr0[kq] = *(const f32x4*)&Whh[(size_t)jbase * HID + k0 + kq * 4];
        wr1[kq] = *(const f32x4*)&Whh[(size_t)(jbase + 1) * HID + k0 + kq * 4];
    }
    #pragma unroll
    for (int kq = 0; kq < 16; ++kq) {
        asm volatile("" : "+v"(wr0[kq]));
        asm volatile("" : "+v"(wr1[kq]));
    }

    // LDS: h double-buffer + xp A/W double-buffers
    __shared__ float hsf[2 * 4352];
    __shared__ float Axs[2][64][68];   // [k][m], m = si*4+bloc
    __shared__ float Wxs[2][64][68];   // [k][n]

    // h staging (r9): thread handles float4 idx tid and tid+512
    const int b0i = tid >> 8,         r0 = tid & 255;
    const int b1i = (tid + 512) >> 8, r1 = (tid + 512) & 255;
    const int exoff0 = (bg * BTILE + b0i) * HID + r0 * 4;
    const int exoff1 = (bg * BTILE + b1i) * HID + r1 * 4;
    const int ldo0 = b0i * 1088 + (r0 >> 4) * 68 + (r0 & 15) * 4;
    const int ldo1 = b1i * 1088 + (r1 >> 4) * 68 + (r1 & 15) * 4;

    // output ownership: lanes c<8 own (batch = c>>1, j = jbase + (c&1))
    const int jout  = jbase + (c & 1);
    const int mybat = c >> 1;
    const int orow  = (bg * BTILE + mybat) * HID + jout;

    // xp-GEMM compute mapping: 512 thr = 16 gty x 32 gtx; micro 4m x 2n.
    const int gty = tid >> 5;
    const int gtx = tid & 31;
    const int jx0 = jt * 64 + gtx * 2;
    const float bias0 = b_ih[jx0] + b_hh[jx0];
    const float bias1 = b_ih[jx0 + 1] + b_hh[jx0 + 1];

    // xp staging mapping (conflict-free)
    const bool isA  = (tid < 256);
    const int  st   = tid & 255;
    const int  srow = st >> 2;         // 0..63 (m for A, n for W)
    const int  kofs = (st & 3) * 4;    // 0,4,8,12

    f32x4 xaccA = {0.f,0.f,0.f,0.f};   // ni=0
    f32x4 xaccB = {0.f,0.f,0.f,0.f};   // ni=1

    auto xp_issue = [&](int sb, int kc, f32x4 v[4]) {
        const float* gp;
        if (isA) {
            gp = &embeds[((size_t)((bg*4 + (srow & 3)) * 512 + sb + (srow >> 2)) << 10)
                         + kc + kofs];
        } else {
            gp = &W_ih[((size_t)(jt*64 + srow) << 10) + kc + kofs];
        }
        #pragma unroll
        for (int s = 0; s < 4; ++s) v[s] = *(const f32x4*)(gp + s * 16);
    };
    auto xp_write = [&](int buf, const f32x4 v[4]) {
        float (*Arr)[68] = isA ? Axs[buf] : Wxs[buf];
        #pragma unroll
        for (int s = 0; s < 4; ++s) {
            Arr[s*16 + kofs + 0][srow] = v[s].x;
            Arr[s*16 + kofs + 1][srow] = v[s].y;
            Arr[s*16 + kofs + 2][srow] = v[s].z;
            Arr[s*16 + kofs + 3][srow] = v[s].w;
        }
    };
    auto xp_compute = [&](int buf) {
        #pragma unroll
        for (int kk = 0; kk < 64; ++kk) {
            f32x4 a4 = *(const f32x4*)&Axs[buf][kk][gty * 4];
            f32x2 w2 = *(const f32x2*)&Wxs[buf][kk][gtx * 2];
            xaccA += a4 * w2.x;
            xaccB += a4 * w2.y;
        }
    };
    auto xp_store = [&](int sbase) {
        float* o = &out[((size_t)((sbase + gty) * 64 + bg * 4) << 10) + jx0];
        *(f32x2*)(o +    0) = f32x2{xaccA.x + bias0, xaccB.x + bias1};
        *(f32x2*)(o + 1024) = f32x2{xaccA.y + bias0, xaccB.y + bias1};
        *(f32x2*)(o + 2048) = f32x2{xaccA.z + bias0, xaccB.z + bias1};
        *(f32x2*)(o + 3072) = f32x2{xaccA.w + bias0, xaccB.w + bias1};
        xaccA = f32x4{0.f,0.f,0.f,0.f};
        xaccB = f32x4{0.f,0.f,0.f,0.f};
    };

    // --- prologue: xp for s in [0,32), 32 quanta ---
    for (int q = 0; q < 32; ++q) {
        const int sb = (q >> 4) << 4;
        const int kc = (q & 15) << 6;
        f32x4 v[4];
        xp_issue(sb, kc, v);
        xp_write(q & 1, v);
        __syncthreads();
        xp_compute(q & 1);
        if ((q & 15) == 15) xp_store(sb);
    }
    __syncthreads();

    // --- t = 0: h0 = tanh(xp0); publish tag 0 into slot 0 ---
    if (c < 8) {
        float h0 = tanhf(out[orow]);
        out[orow] = h0;
        __hip_atomic_store(&exch[orow], h0, __ATOMIC_RELAXED,
                           __HIP_MEMORY_SCOPE_AGENT);
    }

    // --- t = 1 .. SEQ-1 ---
    for (int t = 1; t < SEQ; ++t) {
        float* cur = out + (size_t)t * STEPSZ;

        // xp for this step (self-written >=16 steps ago; plain cached load)
        float xp = 0.f;
        if (c < 8) xp = cur[orow];

        // issue xp staging loads for quantum q = t-1 (hidden under the poll)
        const bool doxp = (t <= 480);
        const int  q    = t - 1;
        const int  xbuf = q & 1;
        const int  sb   = 32 + (q & ~15);
        const int  kc   = (q & 15) << 6;
        f32x4 vstage[4];
        if (doxp) {
            xp_issue(sb, kc, vstage);
            __builtin_amdgcn_sched_barrier(0);
        }

        // poll + fetch h(t-1) — r9 value-tagged protocol
        const float off = 4.0f * (float)((t - 1) & 3);
        const float lo  = off - 1.0f, hi = off + 1.0f;
        const float* eb = exch + ((t - 1) & 1) * SLOT;
        f32x4 v0, v1;
        llc_load4x2_sync(eb + exoff0, eb + exoff1, v0, v1);
        bool ok0 = inrange4(v0, lo, hi);
        bool ok1 = inrange4(v1, lo, hi);
        while (!__all(ok0 && ok1)) {
            __builtin_amdgcn_s_sleep(1);
            if (!ok0) { v0 = llc_load4_sync(eb + exoff0); ok0 = inrange4(v0, lo, hi); }
            if (!ok1) { v1 = llc_load4_sync(eb + exoff1); ok1 = inrange4(v1, lo, hi); }
        }
        v0 -= off;
        v1 -= off;

        // stage h + stage xp, one barrier
        const int bufb = (t & 1) * 4352;
        *(f32x4*)&hsf[bufb + ldo0] = v0;
        *(f32x4*)&hsf[bufb + ldo1] = v1;
        if (doxp) xp_write(xbuf, vstage);
        __syncthreads();

        // h compute (r9)
        float acc[4][2];
        #pragma unroll
        for (int b = 0; b < 4; ++b) {
            const f32x4* hb = (const f32x4*)&hsf[bufb + b * 1088 + c * 68];
            f32x4 s0 = {0.f,0.f,0.f,0.f}, s1 = {0.f,0.f,0.f,0.f};
            #pragma unroll
            for (int kq = 0; kq < 16; ++kq) {
                f32x4 h4 = hb[kq];
                s0 += h4 * wr0[kq];
                s1 += h4 * wr1[kq];
            }
            acc[b][0] = (s0.x + s0.y) + (s0.z + s0.w);
            acc[b][1] = (s1.x + s1.y) + (s1.z + s1.w);
        }
        #pragma unroll
        for (int b = 0; b < 4; ++b) {
            acc[b][0] = red16(acc[b][0]);
            acc[b][1] = red16(acc[b][1]);
        }
        float vb0 = (c & 1) ? acc[0][1] : acc[0][0];
        float vb1 = (c & 1) ? acc[1][1] : acc[1][0];
        float vb2 = (c & 1) ? acc[2][1] : acc[2][0];
        float vb3 = (c & 1) ? acc[3][1] : acc[3][0];
        float vlo = (c & 2) ? vb1 : vb0;
        float vhi = (c & 2) ? vb3 : vb2;
        float v   = (c & 4) ? vhi : vlo;
        if (c < 8) {
            float hv = tanhf(xp + v);
            cur[orow] = hv;
            __hip_atomic_store(&exch[(t & 1) * SLOT + orow],
                               hv + 4.0f * (float)(t & 3),
                               __ATOMIC_RELAXED, __HIP_MEMORY_SCOPE_AGENT);
        }

        // xp quantum compute (overlaps the h-exchange turnaround)
        if (doxp) {
            xp_compute(xbuf);
            if ((t & 15) == 0) xp_store(sb);   // q&15==15 -> block complete
        }
    }
}

// ---------------------------------------------------------------------------
extern "C" void kernel_launch(void* const* d_in, const int* in_sizes, int n_in,
                              void* d_out, int out_size, void* d_ws, size_t ws_size,
                              hipStream_t stream) {
    const float* embeds = (const float*)d_in[0];
    const float* W_ih   = (const float*)d_in[1];
    const float* W_hh   = (const float*)d_in[2];
    const float* b_ih   = (const float*)d_in[3];
    const float* b_hh   = (const float*)d_in[4];
    float* out = (float*)d_out;

    (void)in_sizes; (void)n_in; (void)out_size; (void)ws_size;

    // poison exchange buffer (outside every tag range); graph-captured so
    // re-armed on every replay.
    hipMemsetAsync(d_ws, 0x7F, (size_t)2 * SLOT * sizeof(float), stream);

    // single fused dispatch
    dim3 gR(NJT, NBG);
    rnn_fused<<<gR, 512, 0, stream>>>(embeds, W_ih, W_hh, b_ih, b_hh,
                                      out, (float*)d_ws);
}